// Round 4
// baseline (408.444 us; speedup 1.0000x reference)
//
#include <hip/hip_runtime.h>

typedef unsigned short bhalf;          // bf16 bits
typedef __attribute__((ext_vector_type(4))) float    f32x4;
typedef __attribute__((ext_vector_type(8))) short    s16x8;
typedef __attribute__((ext_vector_type(4))) float    floatx4;
typedef __attribute__((ext_vector_type(4))) unsigned int u32x4;
typedef __attribute__((ext_vector_type(4))) unsigned short u16x4;

#define B_  2
#define S_  2048
#define HID_ 2048
#define NH_ 16
#define HD_ 128
#define M_  (B_*S_)          // 4096
#define MASKV (-10000.0f)

__device__ __forceinline__ bhalf f32_to_bf16(float f) {
    union { float f; unsigned int u; } v; v.f = f;
    unsigned int r = v.u + 0x7FFFu + ((v.u >> 16) & 1u);   // RNE
    return (bhalf)(r >> 16);
}
__device__ __forceinline__ bhalf f32_to_bf16_trunc(float f) {
    union { float f; unsigned int u; } v; v.f = f;
    return (bhalf)(v.u >> 16);
}
__device__ __forceinline__ float bf16_to_f32(bhalf h) {
    union { unsigned int u; float f; } v; v.u = ((unsigned int)h) << 16;
    return v.f;
}

// async global->LDS, 16B per lane; LDS dest = wave-uniform base + lane*16
__device__ __forceinline__ void gl_lds16(const void* g, void* l) {
    __builtin_amdgcn_global_load_lds(
        (const __attribute__((address_space(1))) void*)g,
        (__attribute__((address_space(3))) void*)l, 16, 0, 0);
}

// ---------------- fused cast fp32 -> bf16 for hs + Wq + Wk + Wv ------------
__global__ __launch_bounds__(256) void cast_all(const float* __restrict__ hs,
                                                const float* __restrict__ Wq,
                                                const float* __restrict__ Wk,
                                                const float* __restrict__ Wv,
                                                bhalf* __restrict__ dst) {
    int idx = blockIdx.x * 256 + threadIdx.x;           // 0 .. 5,242,879
    const float* src;
    if (idx < 2097152)      src = hs + (size_t)idx * 4;
    else if (idx < 3145728) src = Wq + (size_t)(idx - 2097152) * 4;
    else if (idx < 4194304) src = Wk + (size_t)(idx - 3145728) * 4;
    else                    src = Wv + (size_t)(idx - 4194304) * 4;
    floatx4 f = *(const floatx4*)src;
    u16x4 o;
    o.x = f32_to_bf16(f.x); o.y = f32_to_bf16(f.y);
    o.z = f32_to_bf16(f.z); o.w = f32_to_bf16(f.w);
    *(u16x4*)(dst + (size_t)idx * 4) = o;
}

// ---------------- fused QKV GEMM (m97 rung): out = hs @ W^T + b ------------
// z==2 (V) writes V^T directly: VT[((b*16+h)*128+d)*2048 + s]
__global__ __launch_bounds__(256) void qkv_gemm(const bhalf* __restrict__ A,
                                                const bhalf* __restrict__ Wb,
                                                const float* __restrict__ bq,
                                                const float* __restrict__ bk,
                                                const float* __restrict__ bv,
                                                bhalf* __restrict__ Out,
                                                bhalf* __restrict__ VTo) {
    __shared__ __align__(16) bhalf As[128 * 32];
    __shared__ __align__(16) bhalf Bs[128 * 32];
    const int tid  = threadIdx.x;
    const int lane = tid & 63, w = tid >> 6;
    const int wy = w >> 1, wx = w & 1;
    const int quad = lane >> 4, l = lane & 15;
    const int m0 = blockIdx.x * 128, n0 = blockIdx.y * 128;
    const int z  = blockIdx.z;
    const bhalf* W    = Wb + (size_t)z * HID_ * HID_;
    const float* bias = (z == 0) ? bq : (z == 1) ? bk : bv;
    bhalf* out        = Out + (size_t)z * M_ * HID_;

    f32x4 acc[4][4] = {};

    for (int kt = 0; kt < HID_; kt += 32) {
#pragma unroll
        for (int j = 0; j < 2; ++j) {
            int slot0 = j * 256 + w * 64;          // wave-uniform
            int slot  = slot0 + lane;
            int row = slot >> 2;
            int cg  = (slot & 3) ^ ((row >> 1) & 3);   // swizzle
            gl_lds16(A + (size_t)(m0 + row) * HID_ + kt + cg * 8, As + slot0 * 8);
            gl_lds16(W + (size_t)(n0 + row) * HID_ + kt + cg * 8, Bs + slot0 * 8);
        }
        __syncthreads();
        s16x8 af[4], bfr[4];
#pragma unroll
        for (int mt = 0; mt < 4; ++mt) {
            int row = wy * 64 + mt * 16 + l;
            int cgs = quad ^ ((row >> 1) & 3);
            af[mt] = *(const s16x8*)(As + (row * 4 + cgs) * 8);
        }
#pragma unroll
        for (int nt = 0; nt < 4; ++nt) {
            int row = wx * 64 + nt * 16 + l;
            int cgs = quad ^ ((row >> 1) & 3);
            bfr[nt] = *(const s16x8*)(Bs + (row * 4 + cgs) * 8);
        }
#pragma unroll
        for (int mt = 0; mt < 4; ++mt)
#pragma unroll
            for (int nt = 0; nt < 4; ++nt)
                acc[mt][nt] = __builtin_amdgcn_mfma_f32_16x16x32_bf16(
                    af[mt], bfr[nt], acc[mt][nt], 0, 0, 0);
        __syncthreads();
    }
    if (z == 2) {
        // V^T epilogue: each (mt,nt) packs 4 consecutive s into one 8B store
#pragma unroll
        for (int mt = 0; mt < 4; ++mt) {
#pragma unroll
            for (int nt = 0; nt < 4; ++nt) {
                int col = n0 + wx * 64 + nt * 16 + l;     // h*128 + d
                float bv_ = bias[col];
                int row0 = m0 + wy * 64 + mt * 16 + quad * 4;  // = b*2048 + s0
                int bb = row0 >> 11, s0 = row0 & 2047;
                u16x4 o;
#pragma unroll
                for (int r = 0; r < 4; ++r) o[r] = f32_to_bf16(acc[mt][nt][r] + bv_);
                *(u16x4*)(VTo + ((size_t)(bb * 16) * 128 + col) * S_ + s0) = o;
            }
        }
    } else {
#pragma unroll
        for (int mt = 0; mt < 4; ++mt) {
#pragma unroll
            for (int nt = 0; nt < 4; ++nt) {
                int col = n0 + wx * 64 + nt * 16 + l;
                float bv_ = bias[col];
#pragma unroll
                for (int r = 0; r < 4; ++r) {
                    int row = m0 + wy * 64 + mt * 16 + quad * 4 + r;
                    out[(size_t)row * HID_ + col] = f32_to_bf16(acc[mt][nt][r] + bv_);
                }
            }
        }
    }
}

// ---------------- RoPE: table precompute + apply ---------------------------
__global__ __launch_bounds__(256) void rope_table(float2* __restrict__ tab) {
    int idx = blockIdx.x * 256 + threadIdx.x;   // 65536 = 2048 s x 32 i
    int i = idx & 31, s = idx >> 5;
    float inv = expf(-(float)i * 0.2878231366242557f);   // ln(10000)/32
    float ang = (float)s * inv;
    tab[idx] = make_float2(sinf(ang), cosf(ang));
}

__global__ __launch_bounds__(256) void rope_apply(bhalf* __restrict__ Qb,
                                                  bhalf* __restrict__ Kb,
                                                  const float2* __restrict__ tab) {
    int flat = blockIdx.x * 256 + threadIdx.x;   // 2,097,152
    int i = flat & 31;
    int h = (flat >> 5) & 15;
    int s = (flat >> 9) & 2047;
    int b = flat >> 20;
    size_t base = ((size_t)(b * S_ + s)) * HID_ + h * HD_ + 2 * i;
    float2 sc = tab[s * 32 + i];
    float c = sc.y, sn = sc.x;
    {
        unsigned int q = *(const unsigned int*)(Qb + base);
        float x0 = bf16_to_f32((bhalf)(q & 0xffff));
        float x1 = bf16_to_f32((bhalf)(q >> 16));
        unsigned int o = (unsigned int)f32_to_bf16(x0 * c - x1 * sn)
                       | ((unsigned int)f32_to_bf16(x1 * c + x0 * sn) << 16);
        *(unsigned int*)(Qb + base) = o;
    }
    {
        unsigned int k = *(const unsigned int*)(Kb + base);
        float x0 = bf16_to_f32((bhalf)(k & 0xffff));
        float x1 = bf16_to_f32((bhalf)(k >> 16));
        unsigned int o = (unsigned int)f32_to_bf16(x0 * c - x1 * sn)
                       | ((unsigned int)f32_to_bf16(x1 * c + x0 * sn) << 16);
        *(unsigned int*)(Kb + base) = o;
    }
}

// ---------------- flash attention, paired 64-row q-tiles, 128-key chunks ---
// Ks  [key=128][x=16]  x = dg ^ (key&7) on low3          (32 KB)
// VTs [d=128][x=16]    x = kg ^ (d&7) on low3            (32 KB)
// Ps overlaid into Ks (dead after QK): per wave 4 KB at Ks + w*2048 elems.
__device__ __forceinline__ void softmax8(const f32x4* sc, float* m_run, f32x4& l_acc,
        f32x4* accO, bhalf* Pw, int row_base, bool diag, int key0,
        const float* am, int quad, int l) {
#pragma unroll
    for (int r = 0; r < 4; ++r) {
        const int qrow = row_base + quad * 4 + r;
        float p[8];
#pragma unroll
        for (int nt = 0; nt < 8; ++nt) {
            float v = sc[nt][r] * 0.08838834764831845f;   // 1/sqrt(128)
            if (diag) { int key = key0 + nt * 16 + l; v = (key > qrow) ? MASKV : v; }
            p[nt] = v + am[nt];
        }
        float mx = fmaxf(fmaxf(fmaxf(p[0], p[1]), fmaxf(p[2], p[3])),
                         fmaxf(fmaxf(p[4], p[5]), fmaxf(p[6], p[7])));
#pragma unroll
        for (int msk = 1; msk < 16; msk <<= 1) mx = fmaxf(mx, __shfl_xor(mx, msk, 64));
        float m_new = fmaxf(m_run[r], mx);
        float alpha = __expf(m_run[r] - m_new);
        m_run[r] = m_new;
        const int m  = quad * 4 + r;
        const int fm = (quad << 1) | (r & 1);
#pragma unroll
        for (int nt = 0; nt < 8; ++nt) {
            float e = __expf(p[nt] - m_new);
            int key = nt * 16 + l;
            Pw[(m * 16 + ((key >> 3) ^ fm)) * 8 + (key & 7)] = f32_to_bf16_trunc(e);
        }
        l_acc[r] *= alpha;
#pragma unroll
        for (int nt = 0; nt < 8; ++nt) accO[nt][r] *= alpha;
    }
}

__global__ __launch_bounds__(256) void flash_attn(const bhalf* __restrict__ Qb,
                                                  const bhalf* __restrict__ Kb,
                                                  const bhalf* __restrict__ VT,
                                                  const float* __restrict__ amask,
                                                  float* __restrict__ out) {
    __shared__ __align__(16) bhalf Ks[128 * 128];   // 32 KB (P regions overlay here)
    __shared__ __align__(16) bhalf VTs[128 * 128];  // 32 KB
    const int tid = threadIdx.x, lane = tid & 63, w = tid >> 6;
    const int quad = lane >> 4, l = lane & 15;
    const int qt = blockIdx.x, bh = blockIdx.y;
    const int b = bh >> 4, h = bh & 15;
    const int row_lo = qt * 64 + w * 16;
    const int row_hi = (31 - qt) * 64 + w * 16;
    const int ch_hi   = (33 - qt) >> 1;             // # 128-key chunks (hi tile)
    const int lo_last = (qt * 64 + 63) >> 7;        // last active chunk (lo tile)

    // Q A-fragments: A[m=l][k=ks*32+quad*8+j]
    s16x8 qfl[4], qfh[4];
    {
        const bhalf* Qlo = Qb + (size_t)(b * S_ + row_lo + l) * HID_ + h * HD_;
        const bhalf* Qhi = Qb + (size_t)(b * S_ + row_hi + l) * HID_ + h * HD_;
#pragma unroll
        for (int ks = 0; ks < 4; ++ks) {
            qfl[ks] = *(const s16x8*)(Qlo + ks * 32 + quad * 8);
            qfh[ks] = *(const s16x8*)(Qhi + ks * 32 + quad * 8);
        }
    }
    // ones B-fragment (bf16 1.0) for the row-sum MFMA
    s16x8 ones;
#pragma unroll
    for (int j = 0; j < 8; ++j) ones[j] = (short)0x3F80;

    float mh[4], ml[4];
#pragma unroll
    for (int r = 0; r < 4; ++r) { mh[r] = -1e30f; ml[r] = -1e30f; }
    f32x4 lh = {}, ll = {};
    f32x4 aoh[8] = {}, aol[8] = {};
    bhalf* Pw = Ks + w * 2048;                      // overlay: valid post-QK
    const int fpl = ((l >> 2) << 1) | (l & 1);      // fp(m=l) for Ps reads

    for (int kc = 0; kc < ch_hi; ++kc) {
        const int key0 = kc * 128;
        // ---- stage K (128x128) and V^T (128x128) swizzled ----
#pragma unroll
        for (int j = 0; j < 8; ++j) {
            int slot0 = j * 256 + w * 64;           // wave-uniform
            int slot  = slot0 + lane;
            int row = slot >> 4, x = slot & 15;
            int g   = (x & 8) | ((x ^ row) & 7);
            gl_lds16(Kb + (size_t)(b * S_ + key0 + row) * HID_ + h * HD_ + g * 8,
                     Ks + slot0 * 8);
            gl_lds16(VT + ((size_t)bh * HD_ + row) * S_ + key0 + g * 8,
                     VTs + slot0 * 8);
        }
        __syncthreads();

        const bool lo_act = (kc <= lo_last);
        const bool dg_hi  = (kc == ch_hi - 1);
        const bool dg_lo  = (kc == lo_last);
        float am[8];
#pragma unroll
        for (int nt = 0; nt < 8; ++nt) am[nt] = amask[b * S_ + key0 + nt * 16 + l];

        // ---- QK^T: K fragments shared across both tiles ----
        f32x4 sh[8] = {}, sl[8] = {};
        if (lo_act) {
#pragma unroll
            for (int nt = 0; nt < 8; ++nt) {
                int key = nt * 16 + l;
#pragma unroll
                for (int ks = 0; ks < 4; ++ks) {
                    int dg = ks * 4 + quad;
                    int x  = (dg & 8) | ((dg ^ key) & 7);
                    s16x8 kf = *(const s16x8*)(Ks + (key * 16 + x) * 8);
                    sh[nt] = __builtin_amdgcn_mfma_f32_16x16x32_bf16(qfh[ks], kf, sh[nt], 0, 0, 0);
                    sl[nt] = __builtin_amdgcn_mfma_f32_16x16x32_bf16(qfl[ks], kf, sl[nt], 0, 0, 0);
                }
            }
        } else {
#pragma unroll
            for (int nt = 0; nt < 8; ++nt) {
                int key = nt * 16 + l;
#pragma unroll
                for (int ks = 0; ks < 4; ++ks) {
                    int dg = ks * 4 + quad;
                    int x  = (dg & 8) | ((dg ^ key) & 7);
                    s16x8 kf = *(const s16x8*)(Ks + (key * 16 + x) * 8);
                    sh[nt] = __builtin_amdgcn_mfma_f32_16x16x32_bf16(qfh[ks], kf, sh[nt], 0, 0, 0);
                }
            }
        }
        __syncthreads();   // all QK reads of Ks done; P regions may now overwrite it

        // ---- hi tile: softmax -> P -> PV (+ ones row-sum) ----
        softmax8(sh, mh, lh, aoh, Pw, row_hi, dg_hi, key0, am, quad, l);
#pragma unroll
        for (int kstep = 0; kstep < 4; ++kstep) {
            int kg = kstep * 4 + quad;
            s16x8 pf = *(const s16x8*)(Pw + (l * 16 + (kg ^ fpl)) * 8);
            lh = __builtin_amdgcn_mfma_f32_16x16x32_bf16(pf, ones, lh, 0, 0, 0);
#pragma unroll
            for (int nt = 0; nt < 8; ++nt) {
                int d = nt * 16 + l;
                int x = (kg & 8) | ((kg ^ d) & 7);
                s16x8 vf = *(const s16x8*)(VTs + (d * 16 + x) * 8);
                aoh[nt] = __builtin_amdgcn_mfma_f32_16x16x32_bf16(pf, vf, aoh[nt], 0, 0, 0);
            }
        }
        // ---- lo tile (Pw reused sequentially within the wave) ----
        if (lo_act) {
            softmax8(sl, ml, ll, aol, Pw, row_lo, dg_lo, key0, am, quad, l);
#pragma unroll
            for (int kstep = 0; kstep < 4; ++kstep) {
                int kg = kstep * 4 + quad;
                s16x8 pf = *(const s16x8*)(Pw + (l * 16 + (kg ^ fpl)) * 8);
                ll = __builtin_amdgcn_mfma_f32_16x16x32_bf16(pf, ones, ll, 0, 0, 0);
#pragma unroll
                for (int nt = 0; nt < 8; ++nt) {
                    int d = nt * 16 + l;
                    int x = (kg & 8) | ((kg ^ d) & 7);
                    s16x8 vf = *(const s16x8*)(VTs + (d * 16 + x) * 8);
                    aol[nt] = __builtin_amdgcn_mfma_f32_16x16x32_bf16(pf, vf, aol[nt], 0, 0, 0);
                }
            }
        }
        __syncthreads();   // all P/V reads done before next staging
    }

    // ---- epilogue: O /= l, fp32 out (B,S,HID) ----
    float invh[4], invl[4];
#pragma unroll
    for (int r = 0; r < 4; ++r) { invh[r] = 1.f / lh[r]; invl[r] = 1.f / ll[r]; }
#pragma unroll
    for (int nt = 0; nt < 8; ++nt) {
        int col = h * HD_ + nt * 16 + l;
#pragma unroll
        for (int r = 0; r < 4; ++r) {
            out[(size_t)(b * S_ + row_hi + quad * 4 + r) * HID_ + col] = aoh[nt][r] * invh[r];
            out[(size_t)(b * S_ + row_lo + quad * 4 + r) * HID_ + col] = aol[nt][r] * invl[r];
        }
    }
}

extern "C" void kernel_launch(void* const* d_in, const int* in_sizes, int n_in,
                              void* d_out, int out_size, void* d_ws, size_t ws_size,
                              hipStream_t stream) {
    const float* hs    = (const float*)d_in[0];
    const float* amask = (const float*)d_in[1];
    const float* Wq    = (const float*)d_in[2];
    const float* bq    = (const float*)d_in[3];
    const float* Wk    = (const float*)d_in[4];
    const float* bk    = (const float*)d_in[5];
    const float* Wv    = (const float*)d_in[6];
    const float* bv    = (const float*)d_in[7];
    float* out = (float*)d_out;

    bhalf* hsb = (bhalf*)d_ws;              // 8,388,608 elems
    bhalf* wqb = hsb + 8388608;             // 3 x 4,194,304 (contiguous)
    bhalf* wkb = wqb + 4194304;
    bhalf* wvb = wkb + 4194304;
    bhalf* Qb  = wvb + 4194304;             // Q,K: 2 x 8,388,608 (contiguous)
    bhalf* Kb  = Qb + 8388608;
    bhalf* VTb = Kb + 8388608;              // V^T written directly by qkv_gemm
    float2* tab = (float2*)(VTb + 8388608); // 65536 float2 = 512 KB

    rope_table<<<256, 256, 0, stream>>>(tab);
    cast_all<<<20480, 256, 0, stream>>>(hs, Wq, Wk, Wv, hsb);
    qkv_gemm<<<dim3(32, 16, 3), 256, 0, stream>>>(hsb, wqb, bq, bk, bv, Qb, VTb);
    rope_apply<<<8192, 256, 0, stream>>>(Qb, Kb, tab);
    flash_attn<<<dim3(16, 32), 256, 0, stream>>>(Qb, Kb, VTb, amask, out);
}

// Round 5
// 373.719 us; speedup vs baseline: 1.0929x; 1.0929x over previous
//
#include <hip/hip_runtime.h>

typedef unsigned short bhalf;          // bf16 bits
typedef __attribute__((ext_vector_type(4))) float    f32x4;
typedef __attribute__((ext_vector_type(8))) short    s16x8;
typedef __attribute__((ext_vector_type(4))) float    floatx4;
typedef __attribute__((ext_vector_type(4))) unsigned int u32x4;
typedef __attribute__((ext_vector_type(4))) unsigned short u16x4;

#define B_  2
#define S_  2048
#define HID_ 2048
#define NH_ 16
#define HD_ 128
#define M_  (B_*S_)          // 4096
#define MASKV (-10000.0f)

__device__ __forceinline__ bhalf f32_to_bf16(float f) {
    union { float f; unsigned int u; } v; v.f = f;
    unsigned int r = v.u + 0x7FFFu + ((v.u >> 16) & 1u);   // RNE
    return (bhalf)(r >> 16);
}
__device__ __forceinline__ bhalf f32_to_bf16_trunc(float f) {
    union { float f; unsigned int u; } v; v.f = f;
    return (bhalf)(v.u >> 16);
}
__device__ __forceinline__ float bf16_to_f32(bhalf h) {
    union { unsigned int u; float f; } v; v.u = ((unsigned int)h) << 16;
    return v.f;
}

// async global->LDS, 16B per lane; LDS dest = wave-uniform base + lane*16
__device__ __forceinline__ void gl_lds16(const void* g, void* l) {
    __builtin_amdgcn_global_load_lds(
        (const __attribute__((address_space(1))) void*)g,
        (__attribute__((address_space(3))) void*)l, 16, 0, 0);
}

// ---------------- fused cast fp32 -> bf16 for hs + Wq + Wk + Wv ------------
__global__ __launch_bounds__(256) void cast_all(const float* __restrict__ hs,
                                                const float* __restrict__ Wq,
                                                const float* __restrict__ Wk,
                                                const float* __restrict__ Wv,
                                                bhalf* __restrict__ dst) {
    int idx = blockIdx.x * 256 + threadIdx.x;           // 0 .. 5,242,879
    const float* src;
    if (idx < 2097152)      src = hs + (size_t)idx * 4;
    else if (idx < 3145728) src = Wq + (size_t)(idx - 2097152) * 4;
    else if (idx < 4194304) src = Wk + (size_t)(idx - 3145728) * 4;
    else                    src = Wv + (size_t)(idx - 4194304) * 4;
    floatx4 f = *(const floatx4*)src;
    u16x4 o;
    o.x = f32_to_bf16(f.x); o.y = f32_to_bf16(f.y);
    o.z = f32_to_bf16(f.z); o.w = f32_to_bf16(f.w);
    *(u16x4*)(dst + (size_t)idx * 4) = o;
}

// ---------------- fused QKV GEMM (m97 rung): out = hs @ W^T + b ------------
// z==2 (V) writes V^T directly: VT[((b*16+h)*128+d)*2048 + s]
__global__ __launch_bounds__(256) void qkv_gemm(const bhalf* __restrict__ A,
                                                const bhalf* __restrict__ Wb,
                                                const float* __restrict__ bq,
                                                const float* __restrict__ bk,
                                                const float* __restrict__ bv,
                                                bhalf* __restrict__ Out,
                                                bhalf* __restrict__ VTo) {
    __shared__ __align__(16) bhalf As[128 * 32];
    __shared__ __align__(16) bhalf Bs[128 * 32];
    const int tid  = threadIdx.x;
    const int lane = tid & 63, w = tid >> 6;
    const int wy = w >> 1, wx = w & 1;
    const int quad = lane >> 4, l = lane & 15;
    const int m0 = blockIdx.x * 128, n0 = blockIdx.y * 128;
    const int z  = blockIdx.z;
    const bhalf* W    = Wb + (size_t)z * HID_ * HID_;
    const float* bias = (z == 0) ? bq : (z == 1) ? bk : bv;
    bhalf* out        = Out + (size_t)z * M_ * HID_;

    f32x4 acc[4][4] = {};

    for (int kt = 0; kt < HID_; kt += 32) {
#pragma unroll
        for (int j = 0; j < 2; ++j) {
            int slot0 = j * 256 + w * 64;          // wave-uniform
            int slot  = slot0 + lane;
            int row = slot >> 2;
            int cg  = (slot & 3) ^ ((row >> 1) & 3);   // swizzle
            gl_lds16(A + (size_t)(m0 + row) * HID_ + kt + cg * 8, As + slot0 * 8);
            gl_lds16(W + (size_t)(n0 + row) * HID_ + kt + cg * 8, Bs + slot0 * 8);
        }
        __syncthreads();
        s16x8 af[4], bfr[4];
#pragma unroll
        for (int mt = 0; mt < 4; ++mt) {
            int row = wy * 64 + mt * 16 + l;
            int cgs = quad ^ ((row >> 1) & 3);
            af[mt] = *(const s16x8*)(As + (row * 4 + cgs) * 8);
        }
#pragma unroll
        for (int nt = 0; nt < 4; ++nt) {
            int row = wx * 64 + nt * 16 + l;
            int cgs = quad ^ ((row >> 1) & 3);
            bfr[nt] = *(const s16x8*)(Bs + (row * 4 + cgs) * 8);
        }
#pragma unroll
        for (int mt = 0; mt < 4; ++mt)
#pragma unroll
            for (int nt = 0; nt < 4; ++nt)
                acc[mt][nt] = __builtin_amdgcn_mfma_f32_16x16x32_bf16(
                    af[mt], bfr[nt], acc[mt][nt], 0, 0, 0);
        __syncthreads();
    }
    if (z == 2) {
#pragma unroll
        for (int mt = 0; mt < 4; ++mt) {
#pragma unroll
            for (int nt = 0; nt < 4; ++nt) {
                int col = n0 + wx * 64 + nt * 16 + l;     // h*128 + d
                float bv_ = bias[col];
                int row0 = m0 + wy * 64 + mt * 16 + quad * 4;  // = b*2048 + s0
                int bb = row0 >> 11, s0 = row0 & 2047;
                u16x4 o;
#pragma unroll
                for (int r = 0; r < 4; ++r) o[r] = f32_to_bf16(acc[mt][nt][r] + bv_);
                *(u16x4*)(VTo + ((size_t)(bb * 16) * 128 + col) * S_ + s0) = o;
            }
        }
    } else {
#pragma unroll
        for (int mt = 0; mt < 4; ++mt) {
#pragma unroll
            for (int nt = 0; nt < 4; ++nt) {
                int col = n0 + wx * 64 + nt * 16 + l;
                float bv_ = bias[col];
#pragma unroll
                for (int r = 0; r < 4; ++r) {
                    int row = m0 + wy * 64 + mt * 16 + quad * 4 + r;
                    out[(size_t)row * HID_ + col] = f32_to_bf16(acc[mt][nt][r] + bv_);
                }
            }
        }
    }
}

// ---------------- RoPE: table precompute + apply ---------------------------
__global__ __launch_bounds__(256) void rope_table(float2* __restrict__ tab) {
    int idx = blockIdx.x * 256 + threadIdx.x;   // 65536 = 2048 s x 32 i
    int i = idx & 31, s = idx >> 5;
    float inv = expf(-(float)i * 0.2878231366242557f);   // ln(10000)/32
    float ang = (float)s * inv;
    tab[idx] = make_float2(sinf(ang), cosf(ang));
}

__global__ __launch_bounds__(256) void rope_apply(bhalf* __restrict__ Qb,
                                                  bhalf* __restrict__ Kb,
                                                  const float2* __restrict__ tab) {
    int flat = blockIdx.x * 256 + threadIdx.x;   // 2,097,152
    int i = flat & 31;
    int h = (flat >> 5) & 15;
    int s = (flat >> 9) & 2047;
    int b = flat >> 20;
    size_t base = ((size_t)(b * S_ + s)) * HID_ + h * HD_ + 2 * i;
    float2 sc = tab[s * 32 + i];
    float c = sc.y, sn = sc.x;
    {
        unsigned int q = *(const unsigned int*)(Qb + base);
        float x0 = bf16_to_f32((bhalf)(q & 0xffff));
        float x1 = bf16_to_f32((bhalf)(q >> 16));
        unsigned int o = (unsigned int)f32_to_bf16(x0 * c - x1 * sn)
                       | ((unsigned int)f32_to_bf16(x1 * c + x0 * sn) << 16);
        *(unsigned int*)(Qb + base) = o;
    }
    {
        unsigned int k = *(const unsigned int*)(Kb + base);
        float x0 = bf16_to_f32((bhalf)(k & 0xffff));
        float x1 = bf16_to_f32((bhalf)(k >> 16));
        unsigned int o = (unsigned int)f32_to_bf16(x0 * c - x1 * sn)
                       | ((unsigned int)f32_to_bf16(x1 * c + x0 * sn) << 16);
        *(unsigned int*)(Kb + base) = o;
    }
}

// ---------------- flash attention: 512-thr block, dbuf staging -------------
// Block (qt, bh): hi tile = 64 rows at (31-qt)*64 (waves 0-3, 16 rows each),
//                 lo tile = 64 rows at qt*64      (waves 4-7).
// 128-key chunks; K/V double-buffered (2 x 32KB each = 128KB LDS).
// P overlays the *current* K buffer after a raw s_barrier (no vmcnt drain,
// so the in-flight next-chunk DMA is not stalled).
__global__ __launch_bounds__(512, 2) void flash_attn(const bhalf* __restrict__ Qb,
                                                     const bhalf* __restrict__ Kb,
                                                     const bhalf* __restrict__ VT,
                                                     const float* __restrict__ amask,
                                                     float* __restrict__ out) {
    __shared__ __align__(16) bhalf Kbuf[2][2048 * 8];   // 2 x 32KB
    __shared__ __align__(16) bhalf Vbuf[2][2048 * 8];   // 2 x 32KB
    const int tid = threadIdx.x, lane = tid & 63, w = tid >> 6;   // w 0..7
    const int quad = lane >> 4, l = lane & 15;
    const int qt = blockIdx.x, bh = blockIdx.y;
    const int b = bh >> 4, h = bh & 15;
    const bool is_hi = (w < 4);
    const int ws = w & 3;
    const int myrow = is_hi ? ((31 - qt) * 64 + ws * 16) : (qt * 64 + ws * 16);
    const int ch_hi   = (33 - qt) >> 1;          // chunks needed by hi tile
    const int lo_last = (qt * 64 + 63) >> 7;     // last active chunk, lo tile
    const int my_last = is_hi ? (ch_hi - 1) : lo_last;

    // Q A-fragments for my 16 rows: A[m=l][k=ks*32+quad*8+j]
    s16x8 qf[4];
    {
        const bhalf* Qrow = Qb + (size_t)(b * S_ + myrow + l) * HID_ + h * HD_;
#pragma unroll
        for (int ks = 0; ks < 4; ++ks)
            qf[ks] = *(const s16x8*)(Qrow + ks * 32 + quad * 8);
    }
    s16x8 ones;
#pragma unroll
    for (int j = 0; j < 8; ++j) ones[j] = (short)0x3F80;

    float m_run[4] = {-1e30f, -1e30f, -1e30f, -1e30f};
    f32x4 l_acc = {};
    f32x4 acc[8] = {};
    const int fpl = ((l >> 2) << 1) | (l & 1);   // fp(m=l) for P reads

    // ---- prologue: stage chunk 0 into buffer 0 ----
#pragma unroll
    for (int j = 0; j < 4; ++j) {
        int slot0 = j * 512 + w * 64;            // wave-uniform
        int slot  = slot0 + lane;
        int row = slot >> 4, x = slot & 15;
        int g   = (x & 8) | ((x ^ row) & 7);
        gl_lds16(Kb + (size_t)(b * S_ + row) * HID_ + h * HD_ + g * 8,
                 &Kbuf[0][slot0 * 8]);
        gl_lds16(VT + ((size_t)bh * HD_ + row) * S_ + g * 8,
                 &Vbuf[0][slot0 * 8]);
    }

    for (int kc = 0; kc < ch_hi; ++kc) {
        const int cur = kc & 1, nxt = cur ^ 1;
        const int key0 = kc * 128;
        __syncthreads();   // drains staging into cur; prior chunk's reads done

        const bool active = (kc <= my_last);
        const bool diag   = (kc == my_last);

        // mask row loads FIRST so their waitcnt doesn't drain the staging below
        float am[8];
        if (active) {
#pragma unroll
            for (int nt = 0; nt < 8; ++nt) am[nt] = amask[b * S_ + key0 + nt * 16 + l];
        }
        // issue next chunk's staging (into nxt) — drained at next top barrier
        if (kc + 1 < ch_hi) {
            const int key1 = key0 + 128;
#pragma unroll
            for (int j = 0; j < 4; ++j) {
                int slot0 = j * 512 + w * 64;
                int slot  = slot0 + lane;
                int row = slot >> 4, x = slot & 15;
                int g   = (x & 8) | ((x ^ row) & 7);
                gl_lds16(Kb + (size_t)(b * S_ + key1 + row) * HID_ + h * HD_ + g * 8,
                         &Kbuf[nxt][slot0 * 8]);
                gl_lds16(VT + ((size_t)bh * HD_ + row) * S_ + key1 + g * 8,
                         &Vbuf[nxt][slot0 * 8]);
            }
        }

        const bhalf* Kc = &Kbuf[cur][0];
        const bhalf* Vc = &Vbuf[cur][0];
        bhalf* Pw = &Kbuf[cur][0] + w * 2048;    // overlay, valid post-QK

        // ---- QK^T ----
        f32x4 s[8] = {};
        if (active) {
#pragma unroll
            for (int nt = 0; nt < 8; ++nt) {
                int key = nt * 16 + l;
#pragma unroll
                for (int ks = 0; ks < 4; ++ks) {
                    int dg = ks * 4 + quad;
                    int x  = (dg & 8) | ((dg ^ key) & 7);
                    s16x8 kf = *(const s16x8*)(Kc + (key * 16 + x) * 8);
                    s[nt] = __builtin_amdgcn_mfma_f32_16x16x32_bf16(qf[ks], kf, s[nt], 0, 0, 0);
                }
            }
        }
        // raw barrier: all QK reads of Kc retired (operands consumed pre-MFMA);
        // deliberately NO vmcnt drain so the nxt-buffer DMA stays in flight.
        __asm__ __volatile__("s_waitcnt lgkmcnt(0)\n\ts_barrier" ::: "memory");

        if (active) {
            // ---- softmax (online) + P write (bf16, swizzled) ----
#pragma unroll
            for (int r = 0; r < 4; ++r) {
                const int qrow = myrow + quad * 4 + r;
                float p[8];
#pragma unroll
                for (int nt = 0; nt < 8; ++nt) {
                    float v = s[nt][r] * 0.08838834764831845f;   // 1/sqrt(128)
                    if (diag) { int key = key0 + nt * 16 + l; v = (key > qrow) ? MASKV : v; }
                    p[nt] = v + am[nt];
                }
                float mx = fmaxf(fmaxf(fmaxf(p[0], p[1]), fmaxf(p[2], p[3])),
                                 fmaxf(fmaxf(p[4], p[5]), fmaxf(p[6], p[7])));
#pragma unroll
                for (int msk = 1; msk < 16; msk <<= 1) mx = fmaxf(mx, __shfl_xor(mx, msk, 64));
                float m_new = fmaxf(m_run[r], mx);
                float alpha = __expf(m_run[r] - m_new);
                m_run[r] = m_new;
                const int m  = quad * 4 + r;
                const int fm = (quad << 1) | (r & 1);
#pragma unroll
                for (int nt = 0; nt < 8; ++nt) {
                    float e = __expf(p[nt] - m_new);
                    int key = nt * 16 + l;
                    Pw[(m * 16 + ((key >> 3) ^ fm)) * 8 + (key & 7)] = f32_to_bf16_trunc(e);
                }
                l_acc[r] *= alpha;
#pragma unroll
                for (int nt = 0; nt < 8; ++nt) acc[nt][r] *= alpha;
            }
            // ---- PV + ones row-sum ----
#pragma unroll
            for (int kstep = 0; kstep < 4; ++kstep) {
                int kg = kstep * 4 + quad;
                s16x8 pf = *(const s16x8*)(Pw + (l * 16 + (kg ^ fpl)) * 8);
                l_acc = __builtin_amdgcn_mfma_f32_16x16x32_bf16(pf, ones, l_acc, 0, 0, 0);
#pragma unroll
                for (int nt = 0; nt < 8; ++nt) {
                    int d = nt * 16 + l;
                    int x = (kg & 8) | ((kg ^ d) & 7);
                    s16x8 vf = *(const s16x8*)(Vc + (d * 16 + x) * 8);
                    acc[nt] = __builtin_amdgcn_mfma_f32_16x16x32_bf16(pf, vf, acc[nt], 0, 0, 0);
                }
            }
        }
    }

    // ---- epilogue: O /= l, fp32 out (B,S,HID) ----
    float inv[4];
#pragma unroll
    for (int r = 0; r < 4; ++r) inv[r] = 1.f / l_acc[r];
#pragma unroll
    for (int nt = 0; nt < 8; ++nt) {
        int col = h * HD_ + nt * 16 + l;
#pragma unroll
        for (int r = 0; r < 4; ++r)
            out[(size_t)(b * S_ + myrow + quad * 4 + r) * HID_ + col] = acc[nt][r] * inv[r];
    }
}

extern "C" void kernel_launch(void* const* d_in, const int* in_sizes, int n_in,
                              void* d_out, int out_size, void* d_ws, size_t ws_size,
                              hipStream_t stream) {
    const float* hs    = (const float*)d_in[0];
    const float* amask = (const float*)d_in[1];
    const float* Wq    = (const float*)d_in[2];
    const float* bq    = (const float*)d_in[3];
    const float* Wk    = (const float*)d_in[4];
    const float* bk    = (const float*)d_in[5];
    const float* Wv    = (const float*)d_in[6];
    const float* bv    = (const float*)d_in[7];
    float* out = (float*)d_out;

    bhalf* hsb = (bhalf*)d_ws;              // 8,388,608 elems
    bhalf* wqb = hsb + 8388608;             // 3 x 4,194,304 (contiguous)
    bhalf* wkb = wqb + 4194304;
    bhalf* wvb = wkb + 4194304;
    bhalf* Qb  = wvb + 4194304;             // Q,K: 2 x 8,388,608 (contiguous)
    bhalf* Kb  = Qb + 8388608;
    bhalf* VTb = Kb + 8388608;              // V^T written directly by qkv_gemm
    float2* tab = (float2*)(VTb + 8388608); // 65536 float2 = 512 KB

    rope_table<<<256, 256, 0, stream>>>(tab);
    cast_all<<<20480, 256, 0, stream>>>(hs, Wq, Wk, Wv, hsb);
    qkv_gemm<<<dim3(32, 16, 3), 256, 0, stream>>>(hsb, wqb, bq, bk, bv, Qb, VTb);
    rope_apply<<<8192, 256, 0, stream>>>(Qb, Kb, tab);
    flash_attn<<<dim3(16, 32), 512, 0, stream>>>(Qb, Kb, VTb, amask, out);
}